// Round 2
// baseline (285.091 us; speedup 1.0000x reference)
//
#include <hip/hip_runtime.h>

#define OUTDIM 512
#define ROWS_PER_BLOCK 16

typedef float vf4 __attribute__((ext_vector_type(4)));

__device__ __forceinline__ float rbf_one(float x0, float x1, float x2,
                                         float c0, float c1, float c2,
                                         float w3) {
    float dx = x0 - c0;
    float dy = x1 - c1;
    float dz = x2 - c2;
    float s  = fmaf(dz, dz, fmaf(dy, dy, dx * dx));
    float d  = sqrtf(s);
    // (35 d^2 + 18 d + 3)
    float p  = fmaf(d, fmaf(d, 35.0f, 18.0f), 3.0f);
    float t  = 1.0f - d;
    float t2 = t * t;
    float t4 = t2 * t2;
    float t6 = t4 * t2;
    return t6 * p * w3;   // w3 = w / 3
}

__global__ __launch_bounds__(256) void rbf_kernel(const float* __restrict__ x,
                                                  const float* __restrict__ centers,
                                                  const float* __restrict__ weights,
                                                  float* __restrict__ out,
                                                  int B) {
    const int tid = threadIdx.x;
    const int q   = tid & 127;   // column quad: columns [4q, 4q+4)
    const int r2  = tid >> 7;    // 0 or 1 (two rows in flight per block pass)
    const int rb  = blockIdx.x * ROWS_PER_BLOCK;

    // ---- load this thread's 4 centers (AoS: 12 contiguous floats) + 4 weights into regs ----
    const vf4* cp4 = (const vf4*)(centers + q * 12);
    const vf4 ca = cp4[0];
    const vf4 cb = cp4[1];
    const vf4 cc = cp4[2];
    // center o=4q+0: (ca.x, ca.y, ca.z)
    // center o=4q+1: (ca.w, cb.x, cb.y)
    // center o=4q+2: (cb.z, cb.w, cc.x)
    // center o=4q+3: (cc.y, cc.z, cc.w)
    const vf4 wv = *(const vf4*)(weights + q * 4);
    const float w30 = wv.x * (1.0f / 3.0f);
    const float w31 = wv.y * (1.0f / 3.0f);
    const float w32 = wv.z * (1.0f / 3.0f);
    const float w33 = wv.w * (1.0f / 3.0f);

#pragma unroll
    for (int rr = 0; rr < ROWS_PER_BLOCK; rr += 2) {
        const int b = rb + rr + r2;
        if (b >= B) break;
        // wave-uniform row load (L1 broadcast)
        const float x0 = x[b * 3 + 0];
        const float x1 = x[b * 3 + 1];
        const float x2 = x[b * 3 + 2];

        vf4 res;
        res.x = rbf_one(x0, x1, x2, ca.x, ca.y, ca.z, w30);
        res.y = rbf_one(x0, x1, x2, ca.w, cb.x, cb.y, w31);
        res.z = rbf_one(x0, x1, x2, cb.z, cb.w, cc.x, w32);
        res.w = rbf_one(x0, x1, x2, cc.y, cc.z, cc.w, w33);

        // streaming store: 268 MB output, no reuse -> nontemporal
        __builtin_nontemporal_store(res, (vf4*)(out + (size_t)b * OUTDIM + q * 4));
    }
}

extern "C" void kernel_launch(void* const* d_in, const int* in_sizes, int n_in,
                              void* d_out, int out_size, void* d_ws, size_t ws_size,
                              hipStream_t stream) {
    const float* x       = (const float*)d_in[0];
    const float* centers = (const float*)d_in[1];
    const float* weights = (const float*)d_in[2];
    float*       out     = (float*)d_out;

    const int B = in_sizes[0] / 3;   // 131072
    const int blocks = (B + ROWS_PER_BLOCK - 1) / ROWS_PER_BLOCK;  // 8192

    hipLaunchKernelGGL(rbf_kernel, dim3(blocks), dim3(256), 0, stream,
                       x, centers, weights, out, B);
}

// Round 3
// 272.549 us; speedup vs baseline: 1.0460x; 1.0460x over previous
//
#include <hip/hip_runtime.h>

#define OUTDIM 512
#define ROWS_PER_BLOCK 16
#define ITERS (ROWS_PER_BLOCK / 2)

typedef float vf4 __attribute__((ext_vector_type(4)));

__device__ __forceinline__ float rbf_one(float x0, float x1, float x2,
                                         float c0, float c1, float c2,
                                         float w3) {
    float dx = x0 - c0;
    float dy = x1 - c1;
    float dz = x2 - c2;
    float s  = fmaf(dz, dz, fmaf(dy, dy, dx * dx));
    float d  = sqrtf(s);
    // (35 d^2 + 18 d + 3)
    float p  = fmaf(d, fmaf(d, 35.0f, 18.0f), 3.0f);
    float t  = 1.0f - d;
    float t2 = t * t;
    float t4 = t2 * t2;
    float t6 = t4 * t2;
    return t6 * p * w3;   // w3 = w / 3
}

__global__ __launch_bounds__(256) void rbf_kernel(const float* __restrict__ x,
                                                  const float* __restrict__ centers,
                                                  const float* __restrict__ weights,
                                                  float* __restrict__ out,
                                                  int B) {
    const int tid = threadIdx.x;
    const int q   = tid & 127;   // column quad: columns [4q, 4q+4)
    const int r2  = tid >> 7;    // 0 or 1 (two rows in flight per block pass)
    const int rb  = blockIdx.x * ROWS_PER_BLOCK;

    // ---- load this thread's 4 centers (AoS: 12 contiguous floats) + 4 weights into regs ----
    const vf4* cp4 = (const vf4*)(centers + q * 12);
    const vf4 ca = cp4[0];
    const vf4 cb = cp4[1];
    const vf4 cc = cp4[2];
    // center o=4q+0: (ca.x, ca.y, ca.z)
    // center o=4q+1: (ca.w, cb.x, cb.y)
    // center o=4q+2: (cb.z, cb.w, cc.x)
    // center o=4q+3: (cc.y, cc.z, cc.w)
    const vf4 wv = *(const vf4*)(weights + q * 4);
    const float w30 = wv.x * (1.0f / 3.0f);
    const float w31 = wv.y * (1.0f / 3.0f);
    const float w32 = wv.z * (1.0f / 3.0f);
    const float w33 = wv.w * (1.0f / 3.0f);

    // ---- prefetch all 8 row-vectors this thread needs (issues all loads at once,
    //      removes per-iteration load->store latency chain) ----
    float xr0[ITERS], xr1[ITERS], xr2[ITERS];
#pragma unroll
    for (int rr = 0; rr < ITERS; ++rr) {
        const int b = rb + rr * 2 + r2;
        xr0[rr] = x[b * 3 + 0];
        xr1[rr] = x[b * 3 + 1];
        xr2[rr] = x[b * 3 + 2];
    }

#pragma unroll
    for (int rr = 0; rr < ITERS; ++rr) {
        const int b = rb + rr * 2 + r2;
        const float x0 = xr0[rr];
        const float x1 = xr1[rr];
        const float x2 = xr2[rr];

        vf4 res;
        res.x = rbf_one(x0, x1, x2, ca.x, ca.y, ca.z, w30);
        res.y = rbf_one(x0, x1, x2, ca.w, cb.x, cb.y, w31);
        res.z = rbf_one(x0, x1, x2, cb.z, cb.w, cc.x, w32);
        res.w = rbf_one(x0, x1, x2, cc.y, cc.z, cc.w, w33);

        // plain streaming store: fill kernels reach 6.4 TB/s with these
        *(vf4*)(out + (size_t)b * OUTDIM + q * 4) = res;
    }
}

extern "C" void kernel_launch(void* const* d_in, const int* in_sizes, int n_in,
                              void* d_out, int out_size, void* d_ws, size_t ws_size,
                              hipStream_t stream) {
    const float* x       = (const float*)d_in[0];
    const float* centers = (const float*)d_in[1];
    const float* weights = (const float*)d_in[2];
    float*       out     = (float*)d_out;

    const int B = in_sizes[0] / 3;   // 131072 (multiple of 16 -> no tail handling needed)
    const int blocks = (B + ROWS_PER_BLOCK - 1) / ROWS_PER_BLOCK;  // 8192

    hipLaunchKernelGGL(rbf_kernel, dim3(blocks), dim3(256), 0, stream,
                       x, centers, weights, out, B);
}